// Round 13
// baseline (527.911 us; speedup 1.0000x reference)
//
#include <hip/hip_runtime.h>

#define NN 20000
#define EE 320000
#define DD 128
#define LL 5
#define EVV 5
#define BNEPS 1e-5f
#define NB 313              // gemm row-blocks: ceil(20000/64)
#define NREP 8              // stats replication factor (atomic de-contention)
#define EMB_BLOCKS 2500     // NN*32/256
#define CVT_BLOCKS 160      // 2*5*128*128/4/256
#define CNT_BLOCKS 1250     // EE/256

typedef __attribute__((ext_vector_type(8))) short bf8_t;           // 8 bf16 (4 VGPRs)
typedef __attribute__((ext_vector_type(4))) float f4_t;            // 4 fp32
typedef __attribute__((ext_vector_type(8))) unsigned short us8;    // 16B of bf16

__device__ inline unsigned short f2bf(float f) {
    union { float f; unsigned u; } v;
    v.f = f;
    unsigned r = v.u + 0x7fffu + ((v.u >> 16) & 1u);  // RTN-even
    return (unsigned short)(r >> 16);
}
__device__ inline float bf2f(unsigned short h) {
    union { unsigned u; float f; } v;
    v.u = ((unsigned)h) << 16;
    return v.f;
}
__device__ inline float4 bf2f4(ushort4 u) {
    float4 f;
    f.x = bf2f(u.x); f.y = bf2f(u.y); f.z = bf2f(u.z); f.w = bf2f(u.w);
    return f;
}
__device__ inline float4 add4(float4 a, float4 b) {
    float4 r;
    r.x = a.x + b.x; r.y = a.y + b.y; r.z = a.z + b.z; r.w = a.w + b.w;
    return r;
}

// BN-affine + optional relu + cross-stitch for one float4 pair (both towers)
__device__ inline void xform4(float4 v1, float4 v2,
                              float4 s1, float4 t1, float4 s2, float4 t2,
                              float c00, float c01, float c10, float c11,
                              int dorelu, float4& n1, float4& n2) {
    float x1, x2, m1, m2;
#define XE(f)                                                    \
    x1 = v1.f * s1.f + t1.f;                                     \
    x2 = v2.f * s2.f + t2.f;                                     \
    x1 = dorelu ? fmaxf(x1, 0.f) : x1;                           \
    x2 = dorelu ? fmaxf(x2, 0.f) : x2;                           \
    m1 = c00 * x1 + c01 * x2;                                    \
    m2 = c10 * m1 + c11 * x2;                                    \
    n1.f = m1;                                                   \
    n2.f = m2;
    XE(x) XE(y) XE(z) XE(w)
#undef XE
}

// Per-thread BN scale/shift (channels 4c..4c+3, both towers) from NREP-replicated raw {sum,sumsq}
__device__ inline void bn_coeffs(const float* __restrict__ statsL,
                                 const float* __restrict__ gall,
                                 const float* __restrict__ btall,
                                 int pl, int c,
                                 float4& s1, float4& t1, float4& s2, float4& t2) {
    const float inv = 1.0f / (float)NN;
    int ch = c * 4;
#define BNC(tw, sv, tv)                                                       \
    {                                                                         \
        const float* gp = gall + (size_t)((tw) * LL + pl) * DD + ch;          \
        const float* bp = btall + (size_t)((tw) * LL + pl) * DD + ch;         \
        float r[4];                                                           \
        _Pragma("unroll") for (int j = 0; j < 4; j++) {                       \
            float sum = 0.f, sq = 0.f;                                        \
            _Pragma("unroll") for (int rep = 0; rep < NREP; rep++) {          \
                sum += statsL[rep * 512 + (tw) * 256 + ch + j];               \
                sq += statsL[rep * 512 + (tw) * 256 + 128 + ch + j];          \
            }                                                                 \
            float mu = sum * inv;                                             \
            float var = sq * inv - mu * mu;                                   \
            float rs = rsqrtf(var + BNEPS);                                   \
            float sc = rs * gp[j];                                            \
            r[j] = sc;                                                        \
            ((float*)&tv)[j] = bp[j] - mu * sc;                               \
        }                                                                     \
        sv.x = r[0]; sv.y = r[1]; sv.z = r[2]; sv.w = r[3];                   \
    }
    BNC(0, s1, t1)
    BNC(1, s2, t2)
#undef BNC
}

__device__ inline ushort4 hi4(float4 v) {
    ushort4 h;
    h.x = f2bf(v.x); h.y = f2bf(v.y); h.z = f2bf(v.z); h.w = f2bf(v.w);
    return h;
}
__device__ inline ushort4 lo4(float4 v, ushort4 h) {
    ushort4 l;
    l.x = f2bf(v.x - bf2f(h.x)); l.y = f2bf(v.y - bf2f(h.y));
    l.z = f2bf(v.z - bf2f(h.z)); l.w = f2bf(v.w - bf2f(h.w));
    return l;
}

// ---------------- prep: embed -> bf16 hi/lo + W hi/lo + etab interleaved bf16 + degree + stats zero ----------------

__global__ __launch_bounds__(256) void prep_kernel(
    const int* __restrict__ x,
    const float4* __restrict__ e1, const float4* __restrict__ e2,
    ushort4* __restrict__ yh, ushort4* __restrict__ yl,
    const float4* __restrict__ Wall,
    ushort4* __restrict__ Wbh, ushort4* __restrict__ Wbl,
    const int* __restrict__ dst, int* __restrict__ deg,
    float* __restrict__ stats,
    const float* __restrict__ etab, unsigned short* __restrict__ etb2) {
    int bid = blockIdx.x;
    int tid = threadIdx.x;
    if (bid < EMB_BLOCKS) {
        int idx = bid * 256 + tid;  // < NN*32 exactly
        int r = idx >> 5, c = idx & 31;
        int v = x[r];
        float4 w1 = e1[v * 32 + c];
        float4 w2 = e2[v * 32 + c];
        ushort4 h = hi4(w1);
        yh[(size_t)r * 64 + c] = h;
        yl[(size_t)r * 64 + c] = lo4(w1, h);
        h = hi4(w2);
        yh[(size_t)r * 64 + 32 + c] = h;
        yl[(size_t)r * 64 + 32 + c] = lo4(w2, h);
    } else if (bid < EMB_BLOCKS + CVT_BLOCKS) {
        int i = (bid - EMB_BLOCKS) * 256 + tid;
        float4 w = Wall[i];
        ushort4 oh = hi4(w);
        Wbh[i] = oh;
        Wbl[i] = lo4(w, oh);
    } else if (bid < EMB_BLOCKS + CVT_BLOCKS + CNT_BLOCKS) {
        int e = (bid - EMB_BLOCKS - CVT_BLOCKS) * 256 + tid;  // < EE exactly
        atomicAdd(&deg[dst[e]], 1);
    } else {
        // zero all layers' replicated BN-stat accumulators: 5 * 8 * 512 floats
        for (int i = 0; i < LL * NREP * 2; i++) stats[i * 256 + tid] = 0.f;
        // etab -> bf16, interleaved layout (l, attr, tower, ch): matches h' row layout
        for (int idx = tid; idx < 2 * LL * EVV * DD; idx += 256) {
            int ch = idx & 127;
            int tw = (idx >> 7) & 1;
            int la = idx >> 8;
            int a = la % EVV;
            int l = la / EVV;
            etb2[idx] = f2bf(etab[((size_t)(tw * LL + l) * EVV + a) * DD + ch]);
        }
    }
}

// ---------------- CSR scan (wave-shuffle based) ----------------

__global__ __launch_bounds__(1024) void scan_kernel(const int* __restrict__ deg,
                                                    int* __restrict__ offs,
                                                    int* __restrict__ pos) {
    __shared__ int wsum[16];
    int t = threadIdx.x;
    int lane = t & 63, wv = t >> 6;
    int base = t * 20;
    int loc[20];
    int s = 0;
#pragma unroll
    for (int i = 0; i < 20; i++) {
        int j = base + i;
        int d = (j < NN) ? deg[j] : 0;
        loc[i] = d;
        s += d;
    }
    int incl = s;
#pragma unroll
    for (int o = 1; o < 64; o <<= 1) {
        int v = __shfl_up(incl, o, 64);
        if (lane >= o) incl += v;
    }
    if (lane == 63) wsum[wv] = incl;
    __syncthreads();
    if (t < 16) {
        int v = wsum[t];
        int iv = v;
#pragma unroll
        for (int o = 1; o < 16; o <<= 1) {
            int u = __shfl_up(iv, o, 64);
            if (t >= o) iv += u;
        }
        wsum[t] = iv - v;  // exclusive wave offset
    }
    __syncthreads();
    int run = wsum[wv] + (incl - s);
#pragma unroll
    for (int i = 0; i < 20; i++) {
        int j = base + i;
        if (j < NN) {
            offs[j] = run;
            pos[j] = run;
            run += loc[i];
        }
    }
}

__global__ __launch_bounds__(256) void scatter_kernel(const int* __restrict__ src,
                                                      const int* __restrict__ dst,
                                                      const int* __restrict__ eattr,
                                                      int* __restrict__ pos,
                                                      int2* __restrict__ erec) {
    int e = blockIdx.x * 256 + threadIdx.x;
    if (e < EE) {
        int d = dst[e];
        int p = atomicAdd(&pos[d], 1);
        erec[p] = make_int2(src[e], eattr[e]);
    }
}

// ---------------- xform: y(hi+lo) -> BN+relu+cross -> h' (hi/lo planes), once per node ----------------

__global__ __launch_bounds__(256) void xform_kernel(
    const ushort4* __restrict__ yh, const ushort4* __restrict__ yl,
    ushort4* __restrict__ hph, ushort4* __restrict__ hpl,
    const float* __restrict__ statsL,
    const float* __restrict__ gall, const float* __restrict__ btall,
    const float* __restrict__ crossp, int pl) {
    int idx = blockIdx.x * 256 + threadIdx.x;  // < NN*32 exactly
    int r = idx >> 5, c = idx & 31;
    float4 s1, t1, s2, t2;
    bn_coeffs(statsL, gall, btall, pl, c, s1, t1, s2, t2);
    float c00 = crossp[0], c01 = crossp[1], c10 = crossp[2], c11 = crossp[3];
    float4 v1 = add4(bf2f4(yh[(size_t)r * 64 + c]), bf2f4(yl[(size_t)r * 64 + c]));
    float4 v2 = add4(bf2f4(yh[(size_t)r * 64 + 32 + c]), bf2f4(yl[(size_t)r * 64 + 32 + c]));
    float4 n1, n2;
    xform4(v1, v2, s1, t1, s2, t2, c00, c01, c10, c11, 1, n1, n2);
    ushort4 h = hi4(n1);
    hph[(size_t)r * 64 + c] = h;
    hpl[(size_t)r * 64 + c] = lo4(n1, h);
    h = hi4(n2);
    hph[(size_t)r * 64 + 32 + c] = h;
    hpl[(size_t)r * 64 + 32 + c] = lo4(n2, h);
}

// ---------------- lean aggregate (R9 form): gather h'(hi)+etab, relu-sum, emit u hi/lo ----------------
// Lane map: slot = lane>>5 (2 edge slots), c = lane&31 (us8 across both towers: c<16 t0, c>=16 t1).

__global__ __launch_bounds__(256) void aggregate_kernel(
    const us8* __restrict__ hph, const us8* __restrict__ hpl,
    const us8* __restrict__ etb2, int layer,
    const int* __restrict__ offs, const int* __restrict__ deg,
    const int2* __restrict__ erec, const float* __restrict__ epsall,
    us8* __restrict__ uo8) {
    int tid = threadIdx.x;
    int node = blockIdx.x * 4 + (tid >> 6);  // grid 5000*4 == NN exactly
    int lane = tid & 63;
    int slot = lane >> 5;
    int c = lane & 31;
    const us8* et = etb2 + (size_t)layer * EVV * 32;

    int off = offs[node];
    int dg = deg[node];
    float a[8];
#pragma unroll
    for (int k = 0; k < 8; k++) a[k] = 0.f;

    int i = 0;
    // main: 8 edges per iter (4 per slot); 16B/lane gathers, minimal VALU
    for (; i + 8 <= dg; i += 8) {
        int2 r0 = erec[off + i + slot];
        int2 r1 = erec[off + i + 2 + slot];
        int2 r2 = erec[off + i + 4 + slot];
        int2 r3 = erec[off + i + 6 + slot];
        us8 h0 = hph[(size_t)r0.x * 32 + c];
        us8 h1 = hph[(size_t)r1.x * 32 + c];
        us8 h2 = hph[(size_t)r2.x * 32 + c];
        us8 h3 = hph[(size_t)r3.x * 32 + c];
        us8 e0 = et[r0.y * 32 + c];
        us8 e1 = et[r1.y * 32 + c];
        us8 e2 = et[r2.y * 32 + c];
        us8 e3 = et[r3.y * 32 + c];
#pragma unroll
        for (int k = 0; k < 8; k++) {
            a[k] += fmaxf(bf2f(h0[k]) + bf2f(e0[k]), 0.f);
            a[k] += fmaxf(bf2f(h1[k]) + bf2f(e1[k]), 0.f);
            a[k] += fmaxf(bf2f(h2[k]) + bf2f(e2[k]), 0.f);
            a[k] += fmaxf(bf2f(h3[k]) + bf2f(e3[k]), 0.f);
        }
    }
    // remainder (<=7), 2 edges per iter, predicated
    for (; i < dg; i += 2) {
        int j = i + slot;
        bool valid = j < dg;
        int e = off + (valid ? j : 0);
        int2 r = erec[e];
        us8 h = hph[(size_t)r.x * 32 + c];
        us8 ev = et[r.y * 32 + c];
        if (valid) {
#pragma unroll
            for (int k = 0; k < 8; k++) a[k] += fmaxf(bf2f(h[k]) + bf2f(ev[k]), 0.f);
        }
    }

    // reduce across the 2 slots
#pragma unroll
    for (int k = 0; k < 8; k++) a[k] += __shfl_xor(a[k], 32, 64);

    // self (exact hi+lo): u = (1+eps)*h' + agg; split hi/lo
    us8 sh = hph[(size_t)node * 32 + c];
    us8 sl = hpl[(size_t)node * 32 + c];
    float ep = 1.0f + epsall[(c >> 4) * LL + layer];
    us8 uh, ul;
#pragma unroll
    for (int k = 0; k < 8; k++) {
        float u = ep * (bf2f(sh[k]) + bf2f(sl[k])) + a[k];
        unsigned short h = f2bf(u);
        uh[k] = h;
        ul[k] = f2bf(u - bf2f(h));
    }
    // u row = 64 us8: [t0hi 16][t1hi 16][t0lo 16][t1lo 16]; slot0 stores hi, slot1 lo
    uo8[(size_t)node * 64 + slot * 32 + c] = slot ? ul : uh;
}

// ---------------- MFMA GEMM (split-precision): y = u @ W^T + b -> bf16 hi/lo; replicated stat atomics ----------------

__global__ __launch_bounds__(256) void gemm_mfma_kernel(
    const unsigned short* __restrict__ ubuf,
    const unsigned short* __restrict__ Wbh, const unsigned short* __restrict__ Wbl,
    const float* __restrict__ ball, int layer,
    unsigned short* __restrict__ yh, unsigned short* __restrict__ yl,
    float* __restrict__ statsL) {
    __shared__ float accS[64 * 4 * 33];   // [(lrow*4 + cg)*33 + k], 2-way-conflict-free
    __shared__ float sP[2][4][DD];        // {sum,sq} x wave x channel
    int tid = threadIdx.x;
    int tower = blockIdx.y;
    const bf8_t* Wh8 = (const bf8_t*)(Wbh + (size_t)(tower * LL + layer) * DD * DD);
    const bf8_t* Wl8 = (const bf8_t*)(Wbl + (size_t)(tower * LL + layer) * DD * DD);
    const float* bias = ball + (size_t)(tower * LL + layer) * DD;
    const bf8_t* u8 = (const bf8_t*)ubuf;

    int wave = tid >> 6, lane = tid & 63;
    int quad = lane >> 4, m = lane & 15;
    int row_base = blockIdx.x * 64 + wave * 16;

    f4_t acc[8];
#pragma unroll
    for (int nt = 0; nt < 8; nt++) {
        acc[nt][0] = 0.f; acc[nt][1] = 0.f; acc[nt][2] = 0.f; acc[nt][3] = 0.f;
    }

    // A row stride = 512 bf16 = 64 bf8 units; tower offset 16; lo at +32.
    int aidx = (row_base + m) * 64 + tower * 16;
#pragma unroll
    for (int kt = 0; kt < 4; kt++) {
        bf8_t ah = u8[aidx + kt * 4 + quad];
        bf8_t al = u8[aidx + 32 + kt * 4 + quad];
#pragma unroll
        for (int nt = 0; nt < 8; nt++) {
            bf8_t bh = Wh8[(nt * 16 + m) * 16 + kt * 4 + quad];
            bf8_t bl = Wl8[(nt * 16 + m) * 16 + kt * 4 + quad];
            acc[nt] = __builtin_amdgcn_mfma_f32_16x16x32_bf16(ah, bh, acc[nt], 0, 0, 0);
            acc[nt] = __builtin_amdgcn_mfma_f32_16x16x32_bf16(al, bh, acc[nt], 0, 0, 0);
            acc[nt] = __builtin_amdgcn_mfma_f32_16x16x32_bf16(ah, bl, acc[nt], 0, 0, 0);
        }
    }

    // Epilogue: D layout col = nt*16 + m, row = quad*4 + reg. Stage into LDS + stats.
#pragma unroll
    for (int nt = 0; nt < 8; nt++) {
        int col = nt * 16 + m;
        float bv = bias[col];
        int cg = col >> 5, kk = col & 31;
        float s = 0.f, q = 0.f;
#pragma unroll
        for (int r = 0; r < 4; r++) {
            int lrow = wave * 16 + quad * 4 + r;
            int row = blockIdx.x * 64 + lrow;
            float v = acc[nt][r] + bv;
            accS[(lrow * 4 + cg) * 33 + kk] = v;
            if (row < NN) { s += v; q += v * v; }
        }
        s += __shfl_xor(s, 16, 64); s += __shfl_xor(s, 32, 64);
        q += __shfl_xor(q, 16, 64); q += __shfl_xor(q, 32, 64);
        if (quad == 0) {
            sP[0][wave][col] = s;
            sP[1][wave][col] = q;
        }
    }
    __syncthreads();

    // vectorized hi/lo stores: thread t -> local row t>>2, col-group t&3 (32 channels)
    {
        int lrow = tid >> 2, cg = tid & 3;
        int grow = blockIdx.x * 64 + lrow;
        if (grow < NN) {
            const float* srcp = &accS[(lrow * 4 + cg) * 33];
            us8* yhp = (us8*)yh;
            us8* ylp = (us8*)yl;
            size_t base = (size_t)grow * 32 + tower * 16 + cg * 4;
#pragma unroll
            for (int j = 0; j < 4; j++) {
                us8 hv, lv;
#pragma unroll
                for (int k = 0; k < 8; k++) {
                    float v = srcp[j * 8 + k];
                    unsigned short h = f2bf(v);
                    hv[k] = h;
                    lv[k] = f2bf(v - bf2f(h));
                }
                yhp[base + j] = hv;
                ylp[base + j] = lv;
            }
        }
    }

    // tid = sq*128 + ch; one atomicAdd/thread into replica (blockIdx.x & 7):
    // 8x less per-address contention; consumers sum the replicas.
    int ch = tid & 127, sq = tid >> 7;
    float v = sP[sq][0][ch] + sP[sq][1][ch] + sP[sq][2][ch] + sP[sq][3][ch];
    atomicAdd(&statsL[(blockIdx.x & (NREP - 1)) * 512 + tower * 256 + tid], v);
}

// ---------------- final epilogue: BN (raw stats) + cross (no relu) from hi+lo -> d_out ----------------

__global__ __launch_bounds__(256) void bn_final_kernel(
    const ushort4* __restrict__ yh, const ushort4* __restrict__ yl,
    float4* __restrict__ o1, float4* __restrict__ o2,
    const float* __restrict__ statsL,
    const float* __restrict__ gall, const float* __restrict__ btall,
    const float* __restrict__ crossp) {
    int idx = blockIdx.x * 256 + threadIdx.x;  // < NN*32 exactly
    int r = idx >> 5, c = idx & 31;
    float4 s1, t1, s2, t2;
    bn_coeffs(statsL, gall, btall, LL - 1, c, s1, t1, s2, t2);
    float c00 = crossp[0], c01 = crossp[1], c10 = crossp[2], c11 = crossp[3];
    float4 v1 = add4(bf2f4(yh[(size_t)r * 64 + c]), bf2f4(yl[(size_t)r * 64 + c]));
    float4 v2 = add4(bf2f4(yh[(size_t)r * 64 + 32 + c]), bf2f4(yl[(size_t)r * 64 + 32 + c]));
    float4 n1, n2;
    xform4(v1, v2, s1, t1, s2, t2, c00, c01, c10, c11, 0, n1, n2);
    o1[(size_t)r * 32 + c] = n1;
    o2[(size_t)r * 32 + c] = n2;
}

// ---------------- launcher ----------------

extern "C" void kernel_launch(void* const* d_in, const int* in_sizes, int n_in,
                              void* d_out, int out_size, void* d_ws, size_t ws_size,
                              hipStream_t stream) {
    const int* x = (const int*)d_in[0];
    const int* eidx = (const int*)d_in[1];
    const int* eattr = (const int*)d_in[2];
    const float* emb1 = (const float*)d_in[3];
    const float* emb2 = (const float*)d_in[4];
    const float* etab = (const float*)d_in[5];
    const float* epsv = (const float*)d_in[6];
    const float* Wall = (const float*)d_in[7];
    const float* ball = (const float*)d_in[8];
    const float* gall = (const float*)d_in[9];
    const float* btall = (const float*)d_in[10];
    const float* cross = (const float*)d_in[11];
    float* out = (float*)d_out;

    const size_t ND = (size_t)NN * DD;  // 2,560,000
    char* p = (char*)d_ws;
    unsigned short* yh = (unsigned short*)p;   p += (size_t)NN * 256 * 2;  // y bf16 hi plane
    unsigned short* yl = (unsigned short*)p;   p += (size_t)NN * 256 * 2;  // y bf16 lo plane
    unsigned short* hph = (unsigned short*)p;  p += (size_t)NN * 256 * 2;  // h' hi plane
    unsigned short* hpl = (unsigned short*)p;  p += (size_t)NN * 256 * 2;  // h' lo plane
    unsigned short* ubuf = (unsigned short*)p; p += (size_t)NN * 512 * 2;  // u hi/lo interleaved
    unsigned short* Wbh = (unsigned short*)p;  p += (size_t)2 * LL * DD * DD * 2;
    unsigned short* Wbl = (unsigned short*)p;  p += (size_t)2 * LL * DD * DD * 2;
    unsigned short* etb2 = (unsigned short*)p; p += (size_t)2 * LL * EVV * DD * 2;
    int* deg = (int*)p;               p += (size_t)NN * 4;
    int* offs = (int*)p;              p += (size_t)NN * 4;
    int* pos = (int*)p;               p += (size_t)NN * 4;
    int2* erec = (int2*)p;            p += (size_t)EE * 8;
    float* stats = (float*)p;         p += (size_t)LL * NREP * 512 * 4;  // per-layer replicated {sum,sq}

    const int* src = eidx;
    const int* dst = eidx + EE;

    hipMemsetAsync(deg, 0, (size_t)NN * 4, stream);
    prep_kernel<<<EMB_BLOCKS + CVT_BLOCKS + CNT_BLOCKS + 1, 256, 0, stream>>>(
        x, (const float4*)emb1, (const float4*)emb2,
        (ushort4*)yh, (ushort4*)yl,
        (const float4*)Wall, (ushort4*)Wbh, (ushort4*)Wbl, dst, deg, stats,
        etab, etb2);
    scan_kernel<<<1, 1024, 0, stream>>>(deg, offs, pos);
    scatter_kernel<<<EE / 256, 256, 0, stream>>>(src, dst, eattr, pos, erec);

    for (int l = 0; l < LL; l++) {
        const unsigned short* hsrc_h = yh;
        const unsigned short* hsrc_l = yl;
        if (l > 0) {
            xform_kernel<<<(NN * 32) / 256, 256, 0, stream>>>(
                (const ushort4*)yh, (const ushort4*)yl,
                (ushort4*)hph, (ushort4*)hpl,
                stats + (size_t)(l - 1) * NREP * 512, gall, btall,
                cross + (l - 1) * 4, l - 1);
            hsrc_h = hph;
            hsrc_l = hpl;
        }
        aggregate_kernel<<<NN / 4, 256, 0, stream>>>(
            (const us8*)hsrc_h, (const us8*)hsrc_l, (const us8*)etb2, l,
            offs, deg, erec, epsv, (us8*)ubuf);
        dim3 g(NB, 2);
        gemm_mfma_kernel<<<g, 256, 0, stream>>>(ubuf, Wbh, Wbl, ball, l, yh, yl,
                                                stats + (size_t)l * NREP * 512);
    }
    bn_final_kernel<<<(NN * 32) / 256, 256, 0, stream>>>(
        (const ushort4*)yh, (const ushort4*)yl, (float4*)out, (float4*)(out + ND),
        stats + (size_t)(LL - 1) * NREP * 512, gall, btall, cross + (LL - 1) * 4);
}

// Round 14
// 501.533 us; speedup vs baseline: 1.0526x; 1.0526x over previous
//
#include <hip/hip_runtime.h>

#define NN 20000
#define EE 320000
#define DD 128
#define LL 5
#define EVV 5
#define BNEPS 1e-5f
#define NB 313              // gemm row-blocks: ceil(20000/64)
#define EMB_BLOCKS 2500     // NN*32/256
#define CVT_BLOCKS 160      // 2*5*128*128/4/256
#define CNT_BLOCKS 1250     // EE/256

typedef __attribute__((ext_vector_type(8))) short bf8_t;           // 8 bf16 (4 VGPRs)
typedef __attribute__((ext_vector_type(4))) float f4_t;            // 4 fp32
typedef __attribute__((ext_vector_type(8))) unsigned short us8;    // 16B of bf16

__device__ inline unsigned short f2bf(float f) {
    union { float f; unsigned u; } v;
    v.f = f;
    unsigned r = v.u + 0x7fffu + ((v.u >> 16) & 1u);  // RTN-even
    return (unsigned short)(r >> 16);
}
__device__ inline float bf2f(unsigned short h) {
    union { unsigned u; float f; } v;
    v.u = ((unsigned)h) << 16;
    return v.f;
}
__device__ inline float4 bf2f4(ushort4 u) {
    float4 f;
    f.x = bf2f(u.x); f.y = bf2f(u.y); f.z = bf2f(u.z); f.w = bf2f(u.w);
    return f;
}
__device__ inline float4 add4(float4 a, float4 b) {
    float4 r;
    r.x = a.x + b.x; r.y = a.y + b.y; r.z = a.z + b.z; r.w = a.w + b.w;
    return r;
}

// BN-affine + optional relu + cross-stitch for one float4 pair (both towers)
__device__ inline void xform4(float4 v1, float4 v2,
                              float4 s1, float4 t1, float4 s2, float4 t2,
                              float c00, float c01, float c10, float c11,
                              int dorelu, float4& n1, float4& n2) {
    float x1, x2, m1, m2;
#define XE(f)                                                    \
    x1 = v1.f * s1.f + t1.f;                                     \
    x2 = v2.f * s2.f + t2.f;                                     \
    x1 = dorelu ? fmaxf(x1, 0.f) : x1;                           \
    x2 = dorelu ? fmaxf(x2, 0.f) : x2;                           \
    m1 = c00 * x1 + c01 * x2;                                    \
    m2 = c10 * m1 + c11 * x2;                                    \
    n1.f = m1;                                                   \
    n2.f = m2;
    XE(x) XE(y) XE(z) XE(w)
#undef XE
}

// Per-thread BN scale/shift (channels 4c..4c+3, both towers) from raw {sum,sumsq}
__device__ inline void bn_coeffs(const float* __restrict__ statsL,
                                 const float* __restrict__ gall,
                                 const float* __restrict__ btall,
                                 int pl, int c,
                                 float4& s1, float4& t1, float4& s2, float4& t2) {
    const float inv = 1.0f / (float)NN;
    int ch = c * 4;
#define BNC(tw, sv, tv)                                                       \
    {                                                                         \
        const float* gp = gall + (size_t)((tw) * LL + pl) * DD + ch;          \
        const float* bp = btall + (size_t)((tw) * LL + pl) * DD + ch;         \
        float r[4];                                                           \
        _Pragma("unroll") for (int j = 0; j < 4; j++) {                       \
            float sum = statsL[(tw) * 256 + ch + j];                          \
            float sq = statsL[(tw) * 256 + 128 + ch + j];                     \
            float mu = sum * inv;                                             \
            float var = sq * inv - mu * mu;                                   \
            float rs = rsqrtf(var + BNEPS);                                   \
            float sc = rs * gp[j];                                            \
            r[j] = sc;                                                        \
            ((float*)&tv)[j] = bp[j] - mu * sc;                               \
        }                                                                     \
        sv.x = r[0]; sv.y = r[1]; sv.z = r[2]; sv.w = r[3];                   \
    }
    BNC(0, s1, t1)
    BNC(1, s2, t2)
#undef BNC
}

__device__ inline ushort4 hi4(float4 v) {
    ushort4 h;
    h.x = f2bf(v.x); h.y = f2bf(v.y); h.z = f2bf(v.z); h.w = f2bf(v.w);
    return h;
}
__device__ inline ushort4 lo4(float4 v, ushort4 h) {
    ushort4 l;
    l.x = f2bf(v.x - bf2f(h.x)); l.y = f2bf(v.y - bf2f(h.y));
    l.z = f2bf(v.z - bf2f(h.z)); l.w = f2bf(v.w - bf2f(h.w));
    return l;
}

// ---------------- prep: embed -> bf16 hi/lo + W hi/lo + etab interleaved bf16 + degree + stats zero ----------------

__global__ __launch_bounds__(256) void prep_kernel(
    const int* __restrict__ x,
    const float4* __restrict__ e1, const float4* __restrict__ e2,
    ushort4* __restrict__ yh, ushort4* __restrict__ yl,
    const float4* __restrict__ Wall,
    ushort4* __restrict__ Wbh, ushort4* __restrict__ Wbl,
    const int* __restrict__ dst, int* __restrict__ deg,
    float* __restrict__ stats,
    const float* __restrict__ etab, unsigned short* __restrict__ etb2) {
    int bid = blockIdx.x;
    int tid = threadIdx.x;
    if (bid < EMB_BLOCKS) {
        int idx = bid * 256 + tid;  // < NN*32 exactly
        int r = idx >> 5, c = idx & 31;
        int v = x[r];
        float4 w1 = e1[v * 32 + c];
        float4 w2 = e2[v * 32 + c];
        ushort4 h = hi4(w1);
        yh[(size_t)r * 64 + c] = h;
        yl[(size_t)r * 64 + c] = lo4(w1, h);
        h = hi4(w2);
        yh[(size_t)r * 64 + 32 + c] = h;
        yl[(size_t)r * 64 + 32 + c] = lo4(w2, h);
    } else if (bid < EMB_BLOCKS + CVT_BLOCKS) {
        int i = (bid - EMB_BLOCKS) * 256 + tid;
        float4 w = Wall[i];
        ushort4 oh = hi4(w);
        Wbh[i] = oh;
        Wbl[i] = lo4(w, oh);
    } else if (bid < EMB_BLOCKS + CVT_BLOCKS + CNT_BLOCKS) {
        int e = (bid - EMB_BLOCKS - CVT_BLOCKS) * 256 + tid;  // < EE exactly
        atomicAdd(&deg[dst[e]], 1);
    } else {
        // zero all layers' raw BN-stat accumulators: 5 * 512 floats
#pragma unroll
        for (int i = 0; i < 10; i++) stats[i * 256 + tid] = 0.f;
        // etab -> bf16, interleaved layout (l, attr, tower, ch): matches h' row layout
        for (int idx = tid; idx < 2 * LL * EVV * DD; idx += 256) {
            int ch = idx & 127;
            int tw = (idx >> 7) & 1;
            int la = idx >> 8;
            int a = la % EVV;
            int l = la / EVV;
            etb2[idx] = f2bf(etab[((size_t)(tw * LL + l) * EVV + a) * DD + ch]);
        }
    }
}

// ---------------- CSR scan (wave-shuffle based) ----------------

__global__ __launch_bounds__(1024) void scan_kernel(const int* __restrict__ deg,
                                                    int* __restrict__ offs,
                                                    int* __restrict__ pos) {
    __shared__ int wsum[16];
    int t = threadIdx.x;
    int lane = t & 63, wv = t >> 6;
    int base = t * 20;
    int loc[20];
    int s = 0;
#pragma unroll
    for (int i = 0; i < 20; i++) {
        int j = base + i;
        int d = (j < NN) ? deg[j] : 0;
        loc[i] = d;
        s += d;
    }
    int incl = s;
#pragma unroll
    for (int o = 1; o < 64; o <<= 1) {
        int v = __shfl_up(incl, o, 64);
        if (lane >= o) incl += v;
    }
    if (lane == 63) wsum[wv] = incl;
    __syncthreads();
    if (t < 16) {
        int v = wsum[t];
        int iv = v;
#pragma unroll
        for (int o = 1; o < 16; o <<= 1) {
            int u = __shfl_up(iv, o, 64);
            if (t >= o) iv += u;
        }
        wsum[t] = iv - v;  // exclusive wave offset
    }
    __syncthreads();
    int run = wsum[wv] + (incl - s);
#pragma unroll
    for (int i = 0; i < 20; i++) {
        int j = base + i;
        if (j < NN) {
            offs[j] = run;
            pos[j] = run;
            run += loc[i];
        }
    }
}

__global__ __launch_bounds__(256) void scatter_kernel(const int* __restrict__ src,
                                                      const int* __restrict__ dst,
                                                      const int* __restrict__ eattr,
                                                      int* __restrict__ pos,
                                                      int2* __restrict__ erec) {
    int e = blockIdx.x * 256 + threadIdx.x;
    if (e < EE) {
        int d = dst[e];
        int p = atomicAdd(&pos[d], 1);
        erec[p] = make_int2(src[e], eattr[e]);
    }
}

// ---------------- xform: y(hi+lo) -> BN+relu+cross -> h' (hi/lo planes), once per node ----------------

__global__ __launch_bounds__(256) void xform_kernel(
    const ushort4* __restrict__ yh, const ushort4* __restrict__ yl,
    ushort4* __restrict__ hph, ushort4* __restrict__ hpl,
    const float* __restrict__ statsL,
    const float* __restrict__ gall, const float* __restrict__ btall,
    const float* __restrict__ crossp, int pl) {
    int idx = blockIdx.x * 256 + threadIdx.x;  // < NN*32 exactly
    int r = idx >> 5, c = idx & 31;
    float4 s1, t1, s2, t2;
    bn_coeffs(statsL, gall, btall, pl, c, s1, t1, s2, t2);
    float c00 = crossp[0], c01 = crossp[1], c10 = crossp[2], c11 = crossp[3];
    float4 v1 = add4(bf2f4(yh[(size_t)r * 64 + c]), bf2f4(yl[(size_t)r * 64 + c]));
    float4 v2 = add4(bf2f4(yh[(size_t)r * 64 + 32 + c]), bf2f4(yl[(size_t)r * 64 + 32 + c]));
    float4 n1, n2;
    xform4(v1, v2, s1, t1, s2, t2, c00, c01, c10, c11, 1, n1, n2);
    ushort4 h = hi4(n1);
    hph[(size_t)r * 64 + c] = h;
    hpl[(size_t)r * 64 + c] = lo4(n1, h);
    h = hi4(n2);
    hph[(size_t)r * 64 + 32 + c] = h;
    hpl[(size_t)r * 64 + 32 + c] = lo4(n2, h);
}

// ---------------- lean aggregate: gather h'(hi) + etab, relu-sum, emit u hi/lo ----------------
// Lane map: slot = lane>>5 (2 edge slots), c = lane&31 (us8 across both towers: c<16 t0, c>=16 t1).

__global__ __launch_bounds__(256) void aggregate_kernel(
    const us8* __restrict__ hph, const us8* __restrict__ hpl,
    const us8* __restrict__ etb2, int layer,
    const int* __restrict__ offs, const int* __restrict__ deg,
    const int2* __restrict__ erec, const float* __restrict__ epsall,
    us8* __restrict__ uo8) {
    int tid = threadIdx.x;
    int node = blockIdx.x * 4 + (tid >> 6);  // grid 5000*4 == NN exactly
    int lane = tid & 63;
    int slot = lane >> 5;
    int c = lane & 31;
    const us8* et = etb2 + (size_t)layer * EVV * 32;

    int off = offs[node];
    int dg = deg[node];
    float a[8];
#pragma unroll
    for (int k = 0; k < 8; k++) a[k] = 0.f;

    int i = 0;
    // main: 8 edges per iter (4 per slot); 16B/lane gathers, minimal VALU
    for (; i + 8 <= dg; i += 8) {
        int2 r0 = erec[off + i + slot];
        int2 r1 = erec[off + i + 2 + slot];
        int2 r2 = erec[off + i + 4 + slot];
        int2 r3 = erec[off + i + 6 + slot];
        us8 h0 = hph[(size_t)r0.x * 32 + c];
        us8 h1 = hph[(size_t)r1.x * 32 + c];
        us8 h2 = hph[(size_t)r2.x * 32 + c];
        us8 h3 = hph[(size_t)r3.x * 32 + c];
        us8 e0 = et[r0.y * 32 + c];
        us8 e1 = et[r1.y * 32 + c];
        us8 e2 = et[r2.y * 32 + c];
        us8 e3 = et[r3.y * 32 + c];
#pragma unroll
        for (int k = 0; k < 8; k++) {
            a[k] += fmaxf(bf2f(h0[k]) + bf2f(e0[k]), 0.f);
            a[k] += fmaxf(bf2f(h1[k]) + bf2f(e1[k]), 0.f);
            a[k] += fmaxf(bf2f(h2[k]) + bf2f(e2[k]), 0.f);
            a[k] += fmaxf(bf2f(h3[k]) + bf2f(e3[k]), 0.f);
        }
    }
    // remainder (<=7), 2 edges per iter, predicated
    for (; i < dg; i += 2) {
        int j = i + slot;
        bool valid = j < dg;
        int e = off + (valid ? j : 0);
        int2 r = erec[e];
        us8 h = hph[(size_t)r.x * 32 + c];
        us8 ev = et[r.y * 32 + c];
        if (valid) {
#pragma unroll
            for (int k = 0; k < 8; k++) a[k] += fmaxf(bf2f(h[k]) + bf2f(ev[k]), 0.f);
        }
    }

    // reduce across the 2 slots
#pragma unroll
    for (int k = 0; k < 8; k++) a[k] += __shfl_xor(a[k], 32, 64);

    // self (exact hi+lo): u = (1+eps)*h' + agg; split hi/lo
    us8 sh = hph[(size_t)node * 32 + c];
    us8 sl = hpl[(size_t)node * 32 + c];
    float ep = 1.0f + epsall[(c >> 4) * LL + layer];
    us8 uh, ul;
#pragma unroll
    for (int k = 0; k < 8; k++) {
        float u = ep * (bf2f(sh[k]) + bf2f(sl[k])) + a[k];
        unsigned short h = f2bf(u);
        uh[k] = h;
        ul[k] = f2bf(u - bf2f(h));
    }
    // u row = 64 us8: [t0hi 16][t1hi 16][t0lo 16][t1lo 16]; slot0 stores hi, slot1 lo
    uo8[(size_t)node * 64 + slot * 32 + c] = slot ? ul : uh;
}

// ---------------- MFMA GEMM (split-precision): y = u @ W^T + b -> bf16 hi/lo (LDS-staged stores) ----------------

__global__ __launch_bounds__(256) void gemm_mfma_kernel(
    const unsigned short* __restrict__ ubuf,
    const unsigned short* __restrict__ Wbh, const unsigned short* __restrict__ Wbl,
    const float* __restrict__ ball, int layer,
    unsigned short* __restrict__ yh, unsigned short* __restrict__ yl,
    float* __restrict__ statsL) {
    __shared__ float accS[64 * 4 * 33];   // [(lrow*4 + cg)*33 + k], 2-way-conflict-free
    __shared__ float sP[2][4][DD];        // {sum,sq} x wave x channel
    int tid = threadIdx.x;
    int tower = blockIdx.y;
    const bf8_t* Wh8 = (const bf8_t*)(Wbh + (size_t)(tower * LL + layer) * DD * DD);
    const bf8_t* Wl8 = (const bf8_t*)(Wbl + (size_t)(tower * LL + layer) * DD * DD);
    const float* bias = ball + (size_t)(tower * LL + layer) * DD;
    const bf8_t* u8 = (const bf8_t*)ubuf;

    int wave = tid >> 6, lane = tid & 63;
    int quad = lane >> 4, m = lane & 15;
    int row_base = blockIdx.x * 64 + wave * 16;

    f4_t acc[8];
#pragma unroll
    for (int nt = 0; nt < 8; nt++) {
        acc[nt][0] = 0.f; acc[nt][1] = 0.f; acc[nt][2] = 0.f; acc[nt][3] = 0.f;
    }

    // A row stride = 512 bf16 = 64 bf8 units; tower offset 16; lo at +32.
    int aidx = (row_base + m) * 64 + tower * 16;
#pragma unroll
    for (int kt = 0; kt < 4; kt++) {
        bf8_t ah = u8[aidx + kt * 4 + quad];
        bf8_t al = u8[aidx + 32 + kt * 4 + quad];
#pragma unroll
        for (int nt = 0; nt < 8; nt++) {
            bf8_t bh = Wh8[(nt * 16 + m) * 16 + kt * 4 + quad];
            bf8_t bl = Wl8[(nt * 16 + m) * 16 + kt * 4 + quad];
            acc[nt] = __builtin_amdgcn_mfma_f32_16x16x32_bf16(ah, bh, acc[nt], 0, 0, 0);
            acc[nt] = __builtin_amdgcn_mfma_f32_16x16x32_bf16(al, bh, acc[nt], 0, 0, 0);
            acc[nt] = __builtin_amdgcn_mfma_f32_16x16x32_bf16(ah, bl, acc[nt], 0, 0, 0);
        }
    }

    // Epilogue: D layout col = nt*16 + m, row = quad*4 + reg. Stage into LDS + stats.
#pragma unroll
    for (int nt = 0; nt < 8; nt++) {
        int col = nt * 16 + m;
        float bv = bias[col];
        int cg = col >> 5, kk = col & 31;
        float s = 0.f, q = 0.f;
#pragma unroll
        for (int r = 0; r < 4; r++) {
            int lrow = wave * 16 + quad * 4 + r;
            int row = blockIdx.x * 64 + lrow;
            float v = acc[nt][r] + bv;
            accS[(lrow * 4 + cg) * 33 + kk] = v;
            if (row < NN) { s += v; q += v * v; }
        }
        s += __shfl_xor(s, 16, 64); s += __shfl_xor(s, 32, 64);
        q += __shfl_xor(q, 16, 64); q += __shfl_xor(q, 32, 64);
        if (quad == 0) {
            sP[0][wave][col] = s;
            sP[1][wave][col] = q;
        }
    }
    __syncthreads();

    // vectorized hi/lo stores: thread t -> local row t>>2, col-group t&3 (32 channels)
    {
        int lrow = tid >> 2, cg = tid & 3;
        int grow = blockIdx.x * 64 + lrow;
        if (grow < NN) {
            const float* srcp = &accS[(lrow * 4 + cg) * 33];
            us8* yhp = (us8*)yh;
            us8* ylp = (us8*)yl;
            size_t base = (size_t)grow * 32 + tower * 16 + cg * 4;
#pragma unroll
            for (int j = 0; j < 4; j++) {
                us8 hv, lv;
#pragma unroll
                for (int k = 0; k < 8; k++) {
                    float v = srcp[j * 8 + k];
                    unsigned short h = f2bf(v);
                    hv[k] = h;
                    lv[k] = f2bf(v - bf2f(h));
                }
                yhp[base + j] = hv;
                ylp[base + j] = lv;
            }
        }
    }

    // tid = sq*128 + ch; one atomicAdd/thread; launch boundary gives visibility
    int ch = tid & 127, sq = tid >> 7;
    float v = sP[sq][0][ch] + sP[sq][1][ch] + sP[sq][2][ch] + sP[sq][3][ch];
    atomicAdd(&statsL[tower * 256 + tid], v);
}

// ---------------- final epilogue: BN (raw stats) + cross (no relu) from hi+lo -> d_out ----------------

__global__ __launch_bounds__(256) void bn_final_kernel(
    const ushort4* __restrict__ yh, const ushort4* __restrict__ yl,
    float4* __restrict__ o1, float4* __restrict__ o2,
    const float* __restrict__ statsL,
    const float* __restrict__ gall, const float* __restrict__ btall,
    const float* __restrict__ crossp) {
    int idx = blockIdx.x * 256 + threadIdx.x;  // < NN*32 exactly
    int r = idx >> 5, c = idx & 31;
    float4 s1, t1, s2, t2;
    bn_coeffs(statsL, gall, btall, LL - 1, c, s1, t1, s2, t2);
    float c00 = crossp[0], c01 = crossp[1], c10 = crossp[2], c11 = crossp[3];
    float4 v1 = add4(bf2f4(yh[(size_t)r * 64 + c]), bf2f4(yl[(size_t)r * 64 + c]));
    float4 v2 = add4(bf2f4(yh[(size_t)r * 64 + 32 + c]), bf2f4(yl[(size_t)r * 64 + 32 + c]));
    float4 n1, n2;
    xform4(v1, v2, s1, t1, s2, t2, c00, c01, c10, c11, 0, n1, n2);
    o1[(size_t)r * 32 + c] = n1;
    o2[(size_t)r * 32 + c] = n2;
}

// ---------------- launcher ----------------

extern "C" void kernel_launch(void* const* d_in, const int* in_sizes, int n_in,
                              void* d_out, int out_size, void* d_ws, size_t ws_size,
                              hipStream_t stream) {
    const int* x = (const int*)d_in[0];
    const int* eidx = (const int*)d_in[1];
    const int* eattr = (const int*)d_in[2];
    const float* emb1 = (const float*)d_in[3];
    const float* emb2 = (const float*)d_in[4];
    const float* etab = (const float*)d_in[5];
    const float* epsv = (const float*)d_in[6];
    const float* Wall = (const float*)d_in[7];
    const float* ball = (const float*)d_in[8];
    const float* gall = (const float*)d_in[9];
    const float* btall = (const float*)d_in[10];
    const float* cross = (const float*)d_in[11];
    float* out = (float*)d_out;

    const size_t ND = (size_t)NN * DD;  // 2,560,000
    char* p = (char*)d_ws;
    unsigned short* yh = (unsigned short*)p;   p += (size_t)NN * 256 * 2;  // y bf16 hi plane
    unsigned short* yl = (unsigned short*)p;   p += (size_t)NN * 256 * 2;  // y bf16 lo plane
    unsigned short* hph = (unsigned short*)p;  p += (size_t)NN * 256 * 2;  // h' hi plane
    unsigned short* hpl = (unsigned short*)p;  p += (size_t)NN * 256 * 2;  // h' lo plane
    unsigned short* ubuf = (unsigned short*)p; p += (size_t)NN * 512 * 2;  // u hi/lo interleaved
    unsigned short* Wbh = (unsigned short*)p;  p += (size_t)2 * LL * DD * DD * 2;
    unsigned short* Wbl = (unsigned short*)p;  p += (size_t)2 * LL * DD * DD * 2;
    unsigned short* etb2 = (unsigned short*)p; p += (size_t)2 * LL * EVV * DD * 2;
    int* deg = (int*)p;               p += (size_t)NN * 4;
    int* offs = (int*)p;              p += (size_t)NN * 4;
    int* pos = (int*)p;               p += (size_t)NN * 4;
    int2* erec = (int2*)p;            p += (size_t)EE * 8;
    float* stats = (float*)p;         p += (size_t)LL * 512 * 4;  // per-layer raw {sum,sq}

    const int* src = eidx;
    const int* dst = eidx + EE;

    hipMemsetAsync(deg, 0, (size_t)NN * 4, stream);
    prep_kernel<<<EMB_BLOCKS + CVT_BLOCKS + CNT_BLOCKS + 1, 256, 0, stream>>>(
        x, (const float4*)emb1, (const float4*)emb2,
        (ushort4*)yh, (ushort4*)yl,
        (const float4*)Wall, (ushort4*)Wbh, (ushort4*)Wbl, dst, deg, stats,
        etab, etb2);
    scan_kernel<<<1, 1024, 0, stream>>>(deg, offs, pos);
    scatter_kernel<<<EE / 256, 256, 0, stream>>>(src, dst, eattr, pos, erec);

    for (int l = 0; l < LL; l++) {
        const unsigned short* hsrc_h = yh;
        const unsigned short* hsrc_l = yl;
        if (l > 0) {
            xform_kernel<<<(NN * 32) / 256, 256, 0, stream>>>(
                (const ushort4*)yh, (const ushort4*)yl,
                (ushort4*)hph, (ushort4*)hpl,
                stats + (size_t)(l - 1) * 512, gall, btall,
                cross + (l - 1) * 4, l - 1);
            hsrc_h = hph;
            hsrc_l = hpl;
        }
        aggregate_kernel<<<NN / 4, 256, 0, stream>>>(
            (const us8*)hsrc_h, (const us8*)hsrc_l, (const us8*)etb2, l,
            offs, deg, erec, epsv, (us8*)ubuf);
        dim3 g(NB, 2);
        gemm_mfma_kernel<<<g, 256, 0, stream>>>(ubuf, Wbh, Wbl, ball, l, yh, yl,
                                                stats + (size_t)l * 512);
    }
    bn_final_kernel<<<(NN * 32) / 256, 256, 0, stream>>>(
        (const ushort4*)yh, (const ushort4*)yl, (float4*)out, (float4*)(out + ND),
        stats + (size_t)(LL - 1) * 512, gall, btall, cross + (LL - 1) * 4);
}